// Round 5
// baseline (115.461 us; speedup 1.0000x reference)
//
#include <hip/hip_runtime.h>

// mask[b, i, j] = (i < len_q[b]) & (j < len_k[b]);  out is int32 (0 / 1)
// B=32, SEQ=2048  ->  out_size = 32*2048*2048 = 134,217,728 ints (512 MiB)
//
// Fill-style grid-stride streaming write: 2048 blocks x 256 threads (exactly
// co-resident, no block re-dispatch), 64 iterations x 1 int4 store/thread.
// Each iteration the whole grid writes one contiguous 8 MiB slab; slab s
// lies entirely within batch b = s>>1, so len lookups are scalar loads.

constexpr int SEQ = 2048;
constexpr int BLOCKS = 2048;
constexpr int THREADS = 256;
constexpr int SLAB_INT4 = BLOCKS * THREADS;       // 524288 int4 = 8 MiB
constexpr int N_SLABS = 64;                        // 2 slabs per batch

typedef int int4v __attribute__((ext_vector_type(4)));

__global__ __launch_bounds__(256) void padmask_kernel(
        const int* __restrict__ len_q,
        const int* __restrict__ len_k,
        int* __restrict__ out) {
    const int tid = blockIdx.x * THREADS + threadIdx.x;   // 0..524287

    // idx = s*SLAB_INT4 + tid;  row = idx>>9, col4 = idx&511
    // SLAB_INT4 % 512 == 0  ->  col is slab-invariant:
    const int j      = (tid & 511) << 2;                  // element column of .x
    const int i_low  = tid >> 9;                          // 0..1023, block-uniform
    int4v* out4 = reinterpret_cast<int4v*>(out);

    #pragma unroll
    for (int s = 0; s < N_SLABS; ++s) {
        const int b  = s >> 1;                            // compile-time after unroll
        const int lq = len_q[b];                          // scalar load (uniform addr)
        const int lk = len_k[b];
        const int i  = ((s & 1) << 10) + i_low;           // row within batch
        const bool qv = (i < lq);
        int4v v;
        v.x = (qv && (j + 0) < lk) ? 1 : 0;
        v.y = (qv && (j + 1) < lk) ? 1 : 0;
        v.z = (qv && (j + 2) < lk) ? 1 : 0;
        v.w = (qv && (j + 3) < lk) ? 1 : 0;
        out4[(size_t)s * SLAB_INT4 + tid] = v;
    }
}

extern "C" void kernel_launch(void* const* d_in, const int* in_sizes, int n_in,
                              void* d_out, int out_size, void* d_ws, size_t ws_size,
                              hipStream_t stream) {
    const int* len_q = (const int*)d_in[0];
    const int* len_k = (const int*)d_in[1];
    int* out = (int*)d_out;

    padmask_kernel<<<BLOCKS, THREADS, 0, stream>>>(len_q, len_k, out);
}

// Round 6
// 83.963 us; speedup vs baseline: 1.3751x; 1.3751x over previous
//
#include <hip/hip_runtime.h>

// mask[b, i, j] = (i < len_q[b]) & (j < len_k[b]);  out is int32 (0 / 1)
// B=32, SEQ=2048  ->  out_size = 32*2048*2048 = 134,217,728 ints (512 MiB)
//
// Gradient across R2/R4/R5: more, smaller blocks = faster for this pure
// store stream. Endpoint config: 131072 blocks x 256 threads, exactly ONE
// int4 store per thread (fire-and-forget; wave exits with stores in flight).

constexpr int SEQ = 2048;
constexpr int THREADS = 256;

typedef int int4v __attribute__((ext_vector_type(4)));

__global__ __launch_bounds__(256) void padmask_kernel(
        const int* __restrict__ len_q,
        const int* __restrict__ len_k,
        int* __restrict__ out) {
    const int idx = blockIdx.x * THREADS + threadIdx.x;   // int4 index, 0..2^27-1

    const int b = blockIdx.x >> 12;          // 4096 blocks per batch sample
    const int i = (idx >> 9) & (SEQ - 1);    // row (block-uniform; 512 int4/row)
    const int j = (idx & 511) << 2;          // element column of lane's .x

    const int lq = len_q[b];
    const int lk = len_k[b];
    const bool qv = (i < lq);

    int4v v;
    v.x = (qv && (j + 0) < lk) ? 1 : 0;
    v.y = (qv && (j + 1) < lk) ? 1 : 0;
    v.z = (qv && (j + 2) < lk) ? 1 : 0;
    v.w = (qv && (j + 3) < lk) ? 1 : 0;
    reinterpret_cast<int4v*>(out)[idx] = v;
}

extern "C" void kernel_launch(void* const* d_in, const int* in_sizes, int n_in,
                              void* d_out, int out_size, void* d_ws, size_t ws_size,
                              hipStream_t stream) {
    const int* len_q = (const int*)d_in[0];
    const int* len_k = (const int*)d_in[1];
    int* out = (int*)d_out;

    const int n_int4 = out_size / 4;                 // 33,554,432
    const int blocks = n_int4 / THREADS;             // 131,072

    padmask_kernel<<<blocks, THREADS, 0, stream>>>(len_q, len_k, out);
}